// Round 6
// baseline (209.600 us; speedup 1.0000x reference)
//
#include <hip/hip_runtime.h>

// NetAndTexture: fused feature-gather + barycentric blend + SH2 eval.
// 8 lanes per pixel-layer: r = role*2 + half.
//   role 0   = frag1 row   (weighted by 1 - d/R^2)  -> out channels 0-7
//   role 1-3 = triangle vertex rows (x barycentric)  -> out channels 8-15
//   half selects 36-float half of the 72-float row; 36%9==0 so both halves
//   share the same (k/9, k%9) channel/coeff pattern -> zero divergence.
// Cache policy: per-pixel streams + output are NON-TEMPORAL (don't evict
// the 144MB features table from L3); features/faces stay normally cached.
// out layout (floats): [HW*16 fg feats][HW*16 bg feats][HW fg mask][HW bg mask]

typedef __attribute__((ext_vector_type(4))) float f32x4;

constexpr float SH_C0 = 0.28209479177387814f;
constexpr float SH_C1 = 0.4886025119029199f;
constexpr float C20 =  1.0925484305920792f;
constexpr float C21 = -1.0925484305920792f;
constexpr float C22 =  0.31539156525252005f;
constexpr float C23 = -1.0925484305920792f;
constexpr float C24 =  0.5462742152960396f;
constexpr float INV_R2 = 1.0f / (0.006f * 0.006f);

__global__ __launch_bounds__(256) void net_tex_nt(
    const float* __restrict__ features,
    const float* __restrict__ dists,
    const float* __restrict__ bary,
    const float* __restrict__ rd,
    const int*  __restrict__ faces,
    const int*  __restrict__ f1idx,
    const int*  __restrict__ p2f,
    float* __restrict__ out,
    int HW, int N)
{
    int q = blockIdx.x * blockDim.x + threadIdx.x;
    int p = q >> 3;            // pixel-layer (uniform across 8-lane group)
    int r = q & 7;
    if (p >= N) return;
    int role = r >> 1;
    int half = r & 1;

    int s  = (p >= HW) ? 1 : 0;
    int hw = p - s * HW;

    // dirs = flip(ray_dirs over H,W) -> rd[k*HW + (HW-1-hw)]
    float x = __builtin_nontemporal_load(rd + (HW   - 1 - hw));
    float y = __builtin_nontemporal_load(rd + (2*HW - 1 - hw));
    float z = __builtin_nontemporal_load(rd + (3*HW - 1 - hw));
    float xx = x*x, yy = y*y, zz = z*z;
    float c[9];
    c[0] = SH_C0;
    c[1] = -SH_C1 * y;
    c[2] =  SH_C1 * z;
    c[3] = -SH_C1 * x;
    c[4] = C20 * x * y;
    c[5] = C21 * y * z;
    c[6] = C22 * (2.0f*zz - xx - yy);
    c[7] = C23 * x * z;
    c[8] = C24 * (xx - yy);

    // Pick this lane's feature row + weight.
    int   idx;
    float w;
    bool  valid;
    if (role == 0) {
        int i1 = __builtin_nontemporal_load(f1idx + p);
        valid = (i1 >= 0);
        idx = valid ? i1 : 0;
        w = 1.0f - __builtin_nontemporal_load(dists + p) * INV_R2;
    } else {
        int f2 = __builtin_nontemporal_load(p2f + p);
        valid = (f2 >= 0);
        int fb = (valid ? f2 : 0) * 3;
        idx = faces[fb + (role - 1)];                       // hot, cached
        w = __builtin_nontemporal_load(bary + (size_t)p * 3 + (role - 1));
    }

    float d[4];
    #pragma unroll
    for (int j = 0; j < 4; j++) d[j] = 0.0f;

    if (valid) {
        const f32x4* row =
            (const f32x4*)(features + (size_t)idx * 72) + half * 9;  // cached
        #pragma unroll
        for (int ch = 0; ch < 9; ch++) {
            f32x4 v = row[ch];
            const int e = ch * 4;          // 36%9==0: same pattern both halves
            d[(e+0)/9] += c[(e+0)%9] * v.x;
            d[(e+1)/9] += c[(e+1)%9] * v.y;
            d[(e+2)/9] += c[(e+2)%9] * v.z;
            d[(e+3)/9] += c[(e+3)%9] * v.w;
        }
        #pragma unroll
        for (int j = 0; j < 4; j++) d[j] *= w;
    }

    // Sum the three vertex rows (roles 1-3) within same half: xor over bits 1,2
    // of r covers roles {0,1,2,3}; role0's contribution is zeroed.
    float sum[4];
    #pragma unroll
    for (int j = 0; j < 4; j++) {
        float t = (role == 0) ? 0.0f : d[j];
        t += __shfl_xor(t, 2, 64);
        t += __shfl_xor(t, 4, 64);
        sum[j] = t;
    }

    // final mask = m1 || m2 over the 8-lane group.
    unsigned long long bal = __ballot(valid);
    int lane = threadIdx.x & 63;
    bool any = ((bal >> (lane & ~7)) & 0xFFULL) != 0;

    f32x4* o = (f32x4*)(out + (size_t)p * 16);
    if (r == 0) {
        f32x4 v = {d[0], d[1], d[2], d[3]};                 // fg ch 0-3
        __builtin_nontemporal_store(v, o + 0);
    } else if (r == 1) {
        f32x4 v = {d[0], d[1], d[2], d[3]};                 // fg ch 4-7
        __builtin_nontemporal_store(v, o + 1);
    } else if (r == 2) {
        f32x4 v = {sum[0], sum[1], sum[2], sum[3]};         // bg ch 8-11
        __builtin_nontemporal_store(v, o + 2);
    } else if (r == 3) {
        f32x4 v = {sum[0], sum[1], sum[2], sum[3]};         // bg ch 12-15
        __builtin_nontemporal_store(v, o + 3);
    } else if (r == 4) {
        __builtin_nontemporal_store(any ? 1.0f : 0.0f,
                                    out + (size_t)2 * HW * 16 + p);
    }
}

extern "C" void kernel_launch(void* const* d_in, const int* in_sizes, int n_in,
                              void* d_out, int out_size, void* d_ws, size_t ws_size,
                              hipStream_t stream)
{
    const float* features = (const float*)d_in[0];
    const float* dists    = (const float*)d_in[1];
    const float* bary     = (const float*)d_in[2];
    const float* rd       = (const float*)d_in[3];
    const int*   faces    = (const int*)d_in[4];
    const int*   f1idx    = (const int*)d_in[5];
    const int*   p2f      = (const int*)d_in[6];
    float* out = (float*)d_out;

    int HW = in_sizes[1] / 2;   // frag1_dists has 2*H*W elements
    int N  = 2 * HW;            // pixel-layers
    long long threads = (long long)N * 8;

    const int block = 256;
    const int grid  = (int)((threads + block - 1) / block);
    hipLaunchKernelGGL(net_tex_nt, dim3(grid), dim3(block), 0, stream,
                       features, dists, bary, rd, faces, f1idx, p2f, out, HW, N);
}

// Round 7
// 196.094 us; speedup vs baseline: 1.0689x; 1.0689x over previous
//
#include <hip/hip_runtime.h>

// NetAndTexture: fused feature-gather + barycentric blend + SH2 eval.
// 8 lanes per pixel-layer: r = role*2 + half.
//   role 0   = frag1 row   (weighted by 1 - d/R^2)  -> out channels 0-7
//   role 1-3 = triangle vertex rows (x barycentric)  -> out channels 8-15
//   half selects 36-float half of the 72-float row; 36%9==0 so both halves
//   share the same (k/9, k%9) channel/coeff pattern -> zero divergence.
// This structure sits on the random-gather memory-system roofline:
// ~745MB/dispatch (667 fetch + 78 write) at ~3.6 TB/s L2-miss service.
// out layout (floats): [HW*16 fg feats][HW*16 bg feats][HW fg mask][HW bg mask]

constexpr float SH_C0 = 0.28209479177387814f;
constexpr float SH_C1 = 0.4886025119029199f;
constexpr float C20 =  1.0925484305920792f;
constexpr float C21 = -1.0925484305920792f;
constexpr float C22 =  0.31539156525252005f;
constexpr float C23 = -1.0925484305920792f;
constexpr float C24 =  0.5462742152960396f;
constexpr float INV_R2 = 1.0f / (0.006f * 0.006f);

__global__ __launch_bounds__(256) void net_tex_kernel8(
    const float* __restrict__ features,
    const float* __restrict__ dists,
    const float* __restrict__ bary,
    const float* __restrict__ rd,
    const int*  __restrict__ faces,
    const int*  __restrict__ f1idx,
    const int*  __restrict__ p2f,
    float* __restrict__ out,
    int HW, int N)
{
    int q = blockIdx.x * blockDim.x + threadIdx.x;
    int p = q >> 3;            // pixel-layer (uniform across 8-lane group)
    int r = q & 7;
    if (p >= N) return;
    int role = r >> 1;
    int half = r & 1;

    int s  = (p >= HW) ? 1 : 0;
    int hw = p - s * HW;

    // dirs = flip(ray_dirs over H,W) -> rd[k*HW + (HW-1-hw)]
    float x = rd[HW   - 1 - hw];
    float y = rd[2*HW - 1 - hw];
    float z = rd[3*HW - 1 - hw];
    float xx = x*x, yy = y*y, zz = z*z;
    float c[9];
    c[0] = SH_C0;
    c[1] = -SH_C1 * y;
    c[2] =  SH_C1 * z;
    c[3] = -SH_C1 * x;
    c[4] = C20 * x * y;
    c[5] = C21 * y * z;
    c[6] = C22 * (2.0f*zz - xx - yy);
    c[7] = C23 * x * z;
    c[8] = C24 * (xx - yy);

    // Pick this lane's feature row + weight.
    int   idx;
    float w;
    bool  valid;
    if (role == 0) {
        int i1 = f1idx[p];
        valid = (i1 >= 0);
        idx = valid ? i1 : 0;
        w = 1.0f - dists[p] * INV_R2;
    } else {
        int f2 = p2f[p];
        valid = (f2 >= 0);
        int fb = (valid ? f2 : 0) * 3;
        idx = faces[fb + (role - 1)];
        w = bary[(size_t)p * 3 + (role - 1)];
    }

    float d[4];
    #pragma unroll
    for (int j = 0; j < 4; j++) d[j] = 0.0f;

    if (valid) {
        const float4* row =
            (const float4*)(features + (size_t)idx * 72) + half * 9;
        #pragma unroll
        for (int ch = 0; ch < 9; ch++) {
            float4 v = row[ch];
            const int e = ch * 4;          // 36%9==0: same pattern both halves
            d[(e+0)/9] += c[(e+0)%9] * v.x;
            d[(e+1)/9] += c[(e+1)%9] * v.y;
            d[(e+2)/9] += c[(e+2)%9] * v.z;
            d[(e+3)/9] += c[(e+3)%9] * v.w;
        }
        #pragma unroll
        for (int j = 0; j < 4; j++) d[j] *= w;
    }

    // Sum the three vertex rows (roles 1-3) within same half: xor over bits 1,2
    // of r covers roles {0,1,2,3}; role0's contribution is zeroed.
    float sum[4];
    #pragma unroll
    for (int j = 0; j < 4; j++) {
        float t = (role == 0) ? 0.0f : d[j];
        t += __shfl_xor(t, 2, 64);
        t += __shfl_xor(t, 4, 64);
        sum[j] = t;
    }

    // final mask = m1 || m2 over the 8-lane group.
    unsigned long long bal = __ballot(valid);
    int lane = threadIdx.x & 63;
    bool any = ((bal >> (lane & ~7)) & 0xFFULL) != 0;

    float4* o = (float4*)(out + (size_t)p * 16);
    if (r == 0) {
        o[0] = make_float4(d[0], d[1], d[2], d[3]);     // fg ch 0-3
    } else if (r == 1) {
        o[1] = make_float4(d[0], d[1], d[2], d[3]);     // fg ch 4-7
    } else if (r == 2) {
        o[2] = make_float4(sum[0], sum[1], sum[2], sum[3]); // bg ch 8-11
    } else if (r == 3) {
        o[3] = make_float4(sum[0], sum[1], sum[2], sum[3]); // bg ch 12-15
    } else if (r == 4) {
        out[(size_t)2 * HW * 16 + p] = any ? 1.0f : 0.0f;
    }
}

extern "C" void kernel_launch(void* const* d_in, const int* in_sizes, int n_in,
                              void* d_out, int out_size, void* d_ws, size_t ws_size,
                              hipStream_t stream)
{
    const float* features = (const float*)d_in[0];
    const float* dists    = (const float*)d_in[1];
    const float* bary     = (const float*)d_in[2];
    const float* rd       = (const float*)d_in[3];
    const int*   faces    = (const int*)d_in[4];
    const int*   f1idx    = (const int*)d_in[5];
    const int*   p2f      = (const int*)d_in[6];
    float* out = (float*)d_out;

    int HW = in_sizes[1] / 2;   // frag1_dists has 2*H*W elements
    int N  = 2 * HW;            // pixel-layers
    long long threads = (long long)N * 8;

    const int block = 256;
    const int grid  = (int)((threads + block - 1) / block);
    hipLaunchKernelGGL(net_tex_kernel8, dim3(grid), dim3(block), 0, stream,
                       features, dists, bary, rd, faces, f1idx, p2f, out, HW, N);
}